// Round 4
// baseline (2087.426 us; speedup 1.0000x reference)
//
#include <hip/hip_runtime.h>
#include <hip/hip_bf16.h>

#define H     1152
#define H3    3456
#define H6    6912
#define NTOK  1024
#define NB    16
#define NHEAD 16
#define HDIM  72
#define MLPD  4608
#define ROWS  (NB*NTOK)   // 16384
#define KSPLIT 16         // mod_kernel k-split (1152/16 = 72)

typedef __hip_bfloat16 bf16;
typedef float f32x4 __attribute__((ext_vector_type(4)));
typedef __bf16 bf16x8 __attribute__((ext_vector_type(8)));
typedef const __attribute__((address_space(1))) void* gptr_as1;
typedef __attribute__((address_space(3))) void* lptr_as3;

__device__ __forceinline__ float b2f(bf16 v){ return __bfloat162float(v); }
__device__ __forceinline__ bf16  f2b(float v){ return __float2bfloat16(v); }

// ---- DPP 16-lane (row) butterfly reductions: VALU-pipe, no ds_swizzle ----
template<int CTRL>
__device__ __forceinline__ float fdpp(float x) {
    int xi = __float_as_int(x);
    int r = __builtin_amdgcn_update_dpp(xi, xi, CTRL, 0xF, 0xF, true);
    return __int_as_float(r);
}
__device__ __forceinline__ float rowmax16(float x) {
    x = fmaxf(x, fdpp<0xB1>(x));    // quad_perm [1,0,3,2]
    x = fmaxf(x, fdpp<0x4E>(x));    // quad_perm [2,3,0,1]
    x = fmaxf(x, fdpp<0x141>(x));   // row_half_mirror
    x = fmaxf(x, fdpp<0x140>(x));   // row_mirror
    return x;
}
__device__ __forceinline__ float rowsum16(float x) {
    x += fdpp<0xB1>(x);
    x += fdpp<0x4E>(x);
    x += fdpp<0x141>(x);
    x += fdpp<0x140>(x);
    return x;
}

// ---------------- mod stage 1: partial[ks][b][col] = sum_{k in slice} swish(c[b,k])*w_mod[k,col] ----------------
__global__ __launch_bounds__(256) void mod_partial_kernel(const float* __restrict__ c,
                                                          const float* __restrict__ w_mod,
                                                          float* __restrict__ partial) {
    const int ks = blockIdx.y;
    const int k0 = ks * (H/KSPLIT);
    __shared__ float sw[NB*(H/KSPLIT)];
    for (int i = threadIdx.x; i < NB*(H/KSPLIT); i += 256) {
        int b = i/(H/KSPLIT), k = i - b*(H/KSPLIT);
        float cv = c[b*H + k0 + k];
        sw[i] = cv / (1.f + __expf(-cv));
    }
    __syncthreads();
    const int col = blockIdx.x*256 + threadIdx.x;   // H6 = 27*256
    float acc[NB];
    #pragma unroll
    for (int b = 0; b < NB; ++b) acc[b] = 0.f;
    for (int k = 0; k < H/KSPLIT; ++k) {
        float wv = w_mod[(long)(k0+k)*H6 + col];
        #pragma unroll
        for (int b = 0; b < NB; ++b) acc[b] += sw[b*(H/KSPLIT)+k] * wv;
    }
    #pragma unroll
    for (int b = 0; b < NB; ++b) partial[((long)ks*NB + b)*H6 + col] = acc[b];
}

// ---------------- mod stage 2: mod[b][col] = sum_ks partial + b_mod[col] ----------------
__global__ __launch_bounds__(256) void mod_reduce_kernel(const float* __restrict__ partial,
                                                         const float* __restrict__ b_mod,
                                                         float* __restrict__ mod) {
    const int idx = blockIdx.x*256 + threadIdx.x;   // NB*H6 = 432*256
    const int col = idx % H6;
    float s = b_mod[col];
    #pragma unroll
    for (int ks = 0; ks < KSPLIT; ++ks) s += partial[(long)ks*NB*H6 + idx];
    mod[idx] = s;
}

// ---------------- row LN + adaLN modulate: out[local bf16] = LN(x_f32[global])*(1+sc)+sh ----------------
__global__ __launch_bounds__(256) void ln_mod_kernel(const float* __restrict__ xin,   // global base (f32)
                                                     const float* __restrict__ mod,
                                                     int sh_off, int sc_off,
                                                     bf16* __restrict__ out,          // chunk-local base
                                                     int row0) {
    const int lrow = blockIdx.x;
    const long grow = (long)row0 + lrow;
    const int b = (int)(grow >> 10);
    const int tid = threadIdx.x;
    const long ibase = grow * H;
    const long obase = (long)lrow * H;
    __shared__ float sred[8];
    float vals[5];
    float sum = 0.f, sq = 0.f;
    #pragma unroll
    for (int i = 0; i < 5; ++i) {
        int cidx = i*256 + tid;
        float v = 0.f;
        if (cidx < H) v = xin[ibase+cidx];
        vals[i] = v; sum += v; sq += v*v;
    }
    #pragma unroll
    for (int off = 32; off > 0; off >>= 1) { sum += __shfl_down(sum, off); sq += __shfl_down(sq, off); }
    int wave = tid >> 6, lane = tid & 63;
    if (lane == 0) { sred[wave] = sum; sred[4+wave] = sq; }
    __syncthreads();
    if (tid == 0) {
        sred[0] = sred[0]+sred[1]+sred[2]+sred[3];
        sred[4] = sred[4]+sred[5]+sred[6]+sred[7];
    }
    __syncthreads();
    float mean = sred[0] * (1.f/H);
    float var  = sred[4] * (1.f/H) - mean*mean;
    float rstd = rsqrtf(var + 1e-6f);
    const float* mrow = mod + b*H6;
    #pragma unroll
    for (int i = 0; i < 5; ++i) {
        int cidx = i*256 + tid;
        if (cidx < H) {
            float y = (vals[i]-mean)*rstd;
            out[obase+cidx] = f2b(y * (1.f + mrow[sc_off+cidx]) + mrow[sh_off+cidx]);
        }
    }
}

// ---------------- f32 -> bf16 transpose (R,C)->(C,R), dims multiple of 32 ----------------
__global__ __launch_bounds__(256) void transpose_kernel(const float* __restrict__ in,
                                                        bf16* __restrict__ out, int R, int C) {
    __shared__ bf16 tile[32][33];
    int c0 = blockIdx.x*32, r0 = blockIdx.y*32;
    int tx = threadIdx.x & 31, ty = threadIdx.x >> 5;
    for (int j = ty; j < 32; j += 8) tile[j][tx] = f2b(in[(long)(r0+j)*C + c0 + tx]);
    __syncthreads();
    for (int j = ty; j < 32; j += 8) out[(long)(c0+j)*R + r0 + tx] = tile[tx][j];
}

// ---------------- m97-style GEMM: A[local M,K]bf16 @ BT[N,K]^T bf16 + bias(f32) ----------------
// EPI 0: C[local] = acc+bias (bf16)
// EPI 1: C[local] = gelu(acc+bias) (bf16)
// EPI 2: Cf[global,f32] = res_f32[global] + gate*(acc+bias)
template<int EPI>
__global__ __launch_bounds__(256) void gemm_bt(const bf16* __restrict__ A, const bf16* __restrict__ BT,
                                               const float* __restrict__ bias,
                                               const float* __restrict__ res, const float* __restrict__ gate,
                                               bf16* __restrict__ C, float* __restrict__ Cf,
                                               int M, int N, int K, int row0) {
    __shared__ __align__(16) bf16 As[128*64];
    __shared__ __align__(16) bf16 Bs[128*64];
    const int tid  = threadIdx.x;
    const int wave = tid >> 6, lane = tid & 63;
    const int wm = wave & 1, wn = wave >> 1;
    const int col = lane & 15, quad = lane >> 4;
    f32x4 acc[4][4];
    #pragma unroll
    for (int i = 0; i < 4; ++i)
        #pragma unroll
        for (int j = 0; j < 4; ++j) acc[i][j] = (f32x4){0.f,0.f,0.f,0.f};

    const long arow0 = (long)blockIdx.y * 128;
    const long brow0 = (long)blockIdx.x * 128;
    const int  srow  = tid >> 3;
    const int  scol  = (tid & 7) * 8;
    const bf16* Ag = A + (arow0 + srow)*(long)K + scol;
    const bf16* Bg = BT + (brow0 + srow)*(long)K + scol;
    bf16* Asl = As + tid*8;
    bf16* Bsl = Bs + tid*8;

    for (int k0 = 0; k0 < K; k0 += 64) {
        __syncthreads();
        #pragma unroll
        for (int i = 0; i < 4; ++i) {
            __builtin_amdgcn_global_load_lds((gptr_as1)(Ag + (long)i*32*K + k0), (lptr_as3)(Asl + i*2048), 16, 0, 0);
            __builtin_amdgcn_global_load_lds((gptr_as1)(Bg + (long)i*32*K + k0), (lptr_as3)(Bsl + i*2048), 16, 0, 0);
        }
        __syncthreads();
        #pragma unroll
        for (int kk = 0; kk < 64; kk += 32) {
            bf16x8 af[4], bfr[4];
            #pragma unroll
            for (int mt = 0; mt < 4; ++mt) af[mt]  = *(const bf16x8*)&As[(wm*64+mt*16+col)*64 + kk + quad*8];
            #pragma unroll
            for (int nt = 0; nt < 4; ++nt) bfr[nt] = *(const bf16x8*)&Bs[(wn*64+nt*16+col)*64 + kk + quad*8];
            #pragma unroll
            for (int mt = 0; mt < 4; ++mt)
                #pragma unroll
                for (int nt = 0; nt < 4; ++nt)
                    acc[mt][nt] = __builtin_amdgcn_mfma_f32_16x16x32_bf16(af[mt], bfr[nt], acc[mt][nt], 0, 0, 0);
        }
    }

    #pragma unroll
    for (int mt = 0; mt < 4; ++mt) {
        #pragma unroll
        for (int nt = 0; nt < 4; ++nt) {
            const int colg = (int)brow0 + wn*64 + nt*16 + col;
            const float bv = bias[colg];
            #pragma unroll
            for (int r = 0; r < 4; ++r) {
                const long rowg = arow0 + wm*64 + mt*16 + quad*4 + r;
                float v = acc[mt][nt][r] + bv;
                if (EPI == 1) {
                    // gelu(tanh approx) via sigmoid: 0.5v(1+tanh(u)) = v*sigmoid(2u)
                    float u = 0.7978845608028654f*(v + 0.044715f*v*v*v);
                    v = v / (1.f + exp2f(-2.885390081777927f*u));
                    C[rowg*(long)N + colg] = f2b(v);
                } else if (EPI == 2) {
                    const long grow = row0 + rowg;
                    float g = gate[(int)(grow>>10)*H6 + colg];
                    Cf[grow*(long)N + colg] = res[grow*(long)N + colg] + g*v;
                } else {
                    C[rowg*(long)N + colg] = f2b(v);
                }
            }
        }
    }
}

// ---------------- per-head LN of q,k (dim 72, bf16 in/out) -> padded [b'][NH][N][96] ----------------
__device__ __forceinline__ void ln72(const bf16* __restrict__ src, const float* __restrict__ gw,
                                     float scale, bf16* __restrict__ dst, int lane) {
    const int i1 = 64 + (lane & 7);
    float e0 = b2f(src[lane]);
    float e1 = (lane < 8) ? b2f(src[i1]) : 0.f;
    float s = e0 + e1;
    #pragma unroll
    for (int off = 32; off > 0; off >>= 1) s += __shfl_xor(s, off);
    float mean = s * (1.f/72.f);
    float d0 = e0 - mean;
    float d1 = (lane < 8) ? (e1 - mean) : 0.f;
    float sq = d0*d0 + d1*d1;
    #pragma unroll
    for (int off = 32; off > 0; off >>= 1) sq += __shfl_xor(sq, off);
    float rstd = rsqrtf(sq*(1.f/72.f) + 1e-6f);
    dst[lane] = f2b(d0*rstd*gw[lane]*scale);
    if (lane < 32) {
        float y1 = (lane < 8) ? d1*rstd*gw[i1]*scale : 0.f;
        dst[64+lane] = f2b(y1);
    }
}

__global__ __launch_bounds__(256) void qk_ln_kernel(const bf16* __restrict__ qkv,  // chunk-local
                                                    const float* __restrict__ g_q, const float* __restrict__ g_k,
                                                    bf16* __restrict__ qln, bf16* __restrict__ kln) {
    const int wave = threadIdx.x >> 6, lane = threadIdx.x & 63;
    const long g  = (long)blockIdx.x*4 + wave;     // < Bc*NHEAD*NTOK
    const int  n  = (int)(g & 1023);
    const long bh = g >> 10;                        // local b*16 + h
    const int  h  = (int)(bh & 15);
    const int  b  = (int)(bh >> 4);
    const bf16* src = qkv + ((long)b*NTOK + n)*H3 + h*HDIM;
    // q scale = HD^-0.5 * log2(e)  (softmax computed in exp2 domain)
    ln72(src,     g_q, 0.11785113019775793f * 1.4426950408889634f, qln + (bh*NTOK + n)*96, lane);
    ln72(src + H, g_k, 1.f,                  kln + (bh*NTOK + n)*96, lane);
}

// ---------------- V -> VT [b'][NH][80][NTOK] (pad rows 72..79 = 0), bf16 ----------------
__global__ __launch_bounds__(256) void v_transpose_kernel(const bf16* __restrict__ qkv, bf16* __restrict__ vt) {
    const int n0 = blockIdx.x*64;
    const int h = blockIdx.y, b = blockIdx.z;      // b local
    __shared__ bf16 tile[64][80];
    const long srcbase = ((long)b*NTOK + n0)*H3 + 2*H + h*HDIM;
    for (int idx = threadIdx.x; idx < 64*72; idx += 256) {
        int n = idx/72, d = idx - n*72;
        tile[n][d] = qkv[srcbase + (long)n*H3 + d];
    }
    for (int idx = threadIdx.x; idx < 64*8; idx += 256) {
        int n = idx >> 3, d = idx & 7;
        tile[n][72+d] = f2b(0.f);
    }
    __syncthreads();
    const long dstbase = ((long)(b*NHEAD + h)*80)*NTOK + n0;
    for (int idx = threadIdx.x; idx < 80*64; idx += 256) {
        int d = idx >> 6, n = idx & 63;
        vt[dstbase + (long)d*NTOK + n] = tile[n][d];
    }
}

// ---------------- flash attention, 2-way KV split, KVBLK=64, XCD-aware bh mapping ----------------
// 1D grid: NBLK = 256*Bc blocks (runs on XCD L%8 by round-robin). Mapping gives each XCD
// a contiguous set of (b,h) pairs so K/V stay resident in that XCD's L2.
// 512 threads = 8 waves. Wave w: qg = w&3 (16 q rows), half = w>>2 (kv range).
#define PSTR 72
__global__ __launch_bounds__(512) void attn_kernel(const bf16* __restrict__ qln, const bf16* __restrict__ kln,
                                                   const bf16* __restrict__ vt, bf16* __restrict__ o,
                                                   int Bc) {
    const int tid = threadIdx.x;
    const int wave = tid >> 6, lane = tid & 63;
    const int qg = wave & 3, half = wave >> 2;
    const int col = lane & 15, quad = lane >> 4;

    // XCD-aware decomposition of linear block id
    const int L = blockIdx.x;
    const int P_ = 2*Bc;                 // bh per XCD = 16*Bc/8
    const int c8 = L & 7;
    const int j  = L >> 3;               // [0, 32*Bc)
    const int bh_l = c8*P_ + (j % P_);   // [0, 16*Bc)
    const int qt   = j / P_;             // [0, 16)
    const int b = bh_l >> 4, h = bh_l & 15;
    const long bh = bh_l;

    const int q0 = qt*64 + qg*16;
    const bf16* qb = qln + bh*NTOK*96;
    const bf16* kb = kln + bh*NTOK*96;
    const bf16* vb = vt  + bh*80*NTOK;

    // LDS: [0,18432) = 8 per-wave P tiles (16 rows x stride 72 bf16 = 2304B each)
    // merge (after sync): O [0,20480) f32x4; M [20480,24576); L [24576,28672)
    __shared__ __align__(16) char smraw[28672];
    bf16* pw = (bf16*)smraw + wave*(16*PSTR);
    f32x4* Osm = (f32x4*)smraw;
    f32x4* Msm = (f32x4*)(smraw + 20480);
    f32x4* Lsm = (f32x4*)(smraw + 24576);

    bf16x8 qf[3];
    #pragma unroll
    for (int ks = 0; ks < 3; ++ks) qf[ks] = *(const bf16x8*)&qb[(q0+col)*96 + ks*32 + quad*8];

    f32x4 oacc[5];
    #pragma unroll
    for (int i = 0; i < 5; ++i) oacc[i] = (f32x4){0.f,0.f,0.f,0.f};
    float mrow[4], lrow[4];
    #pragma unroll
    for (int r = 0; r < 4; ++r) { mrow[r] = -1e30f; lrow[r] = 0.f; }

    const int kvbeg = half*512, kvend = kvbeg + 512;
    for (int kv0 = kvbeg; kv0 < kvend; kv0 += 64) {
        // ---- QK^T: S[16q x 64k] ----
        f32x4 s[4];
        #pragma unroll
        for (int j4 = 0; j4 < 4; ++j4) s[j4] = (f32x4){0.f,0.f,0.f,0.f};
        #pragma unroll
        for (int j4 = 0; j4 < 4; ++j4)
            #pragma unroll
            for (int ks = 0; ks < 3; ++ks) {
                bf16x8 kf = *(const bf16x8*)&kb[(kv0 + j4*16 + col)*96 + ks*32 + quad*8];
                s[j4] = __builtin_amdgcn_mfma_f32_16x16x32_bf16(qf[ks], kf, s[j4], 0, 0, 0);
            }
        // ---- online softmax (exp2 domain), DPP reductions ----
        float alpha[4];
        #pragma unroll
        for (int r = 0; r < 4; ++r) {
            float tm = fmaxf(fmaxf(s[0][r], s[1][r]), fmaxf(s[2][r], s[3][r]));
            tm = rowmax16(tm);
            float mn = fmaxf(mrow[r], tm);
            alpha[r] = exp2f(mrow[r] - mn);
            float p0 = exp2f(s[0][r] - mn);
            float p1 = exp2f(s[1][r] - mn);
            float p2 = exp2f(s[2][r] - mn);
            float p3 = exp2f(s[3][r] - mn);
            float ts = rowsum16((p0+p1)+(p2+p3));
            lrow[r] = lrow[r]*alpha[r] + ts;
            mrow[r] = mn;
            const int prow = quad*4 + r;
            pw[prow*PSTR + col]      = f2b(p0);
            pw[prow*PSTR + 16 + col] = f2b(p1);
            pw[prow*PSTR + 32 + col] = f2b(p2);
            pw[prow*PSTR + 48 + col] = f2b(p3);
        }
        // ---- deferred rescale: alpha==1.0 exactly when row max unchanged ----
        if (__any(alpha[0]+alpha[1]+alpha[2]+alpha[3] < 4.f)) {
            #pragma unroll
            for (int i = 0; i < 5; ++i)
                #pragma unroll
                for (int r = 0; r < 4; ++r) oacc[i][r] *= alpha[r];
        }
        asm volatile("s_waitcnt lgkmcnt(0)" ::: "memory");
        bf16x8 pf0 = *(const bf16x8*)&pw[col*PSTR + quad*8];
        bf16x8 pf1 = *(const bf16x8*)&pw[col*PSTR + 32 + quad*8];
        #pragma unroll
        for (int nt = 0; nt < 5; ++nt) {
            bf16x8 vf0 = *(const bf16x8*)&vb[(nt*16+col)*NTOK + kv0 + quad*8];
            bf16x8 vf1 = *(const bf16x8*)&vb[(nt*16+col)*NTOK + kv0 + 32 + quad*8];
            oacc[nt] = __builtin_amdgcn_mfma_f32_16x16x32_bf16(pf0, vf0, oacc[nt], 0, 0, 0);
            oacc[nt] = __builtin_amdgcn_mfma_f32_16x16x32_bf16(pf1, vf1, oacc[nt], 0, 0, 0);
        }
    }

    // ---- merge the two KV halves ----
    __syncthreads();   // all waves done with P tiles (merge buffers alias them)
    if (half) {
        f32x4 mv, lv;
        #pragma unroll
        for (int r = 0; r < 4; ++r) { mv[r] = mrow[r]; lv[r] = lrow[r]; }
        Msm[qg*64 + lane] = mv;
        Lsm[qg*64 + lane] = lv;
        #pragma unroll
        for (int nt = 0; nt < 5; ++nt) Osm[(qg*5 + nt)*64 + lane] = oacc[nt];
    }
    __syncthreads();
    if (!half) {
        f32x4 mB = Msm[qg*64 + lane];
        f32x4 lB = Lsm[qg*64 + lane];
        float aA[4], aB[4], inv[4];
        #pragma unroll
        for (int r = 0; r < 4; ++r) {
            float ms = fmaxf(mrow[r], mB[r]);
            aA[r] = exp2f(mrow[r] - ms);
            aB[r] = exp2f(mB[r] - ms);
            float ls = lrow[r]*aA[r] + lB[r]*aB[r];
            inv[r] = 1.f / ls;
        }
        #pragma unroll
        for (int nt = 0; nt < 5; ++nt) {
            f32x4 oB = Osm[(qg*5 + nt)*64 + lane];
            int d = nt*16 + col;
            if (d < HDIM) {
                #pragma unroll
                for (int r = 0; r < 4; ++r) {
                    int qrow = q0 + quad*4 + r;
                    o[((long)b*NTOK + qrow)*H + h*HDIM + d] = f2b((oacc[nt][r]*aA[r] + oB[r]*aB[r])*inv[r]);
                }
            }
        }
    }
}

extern "C" void kernel_launch(void* const* d_in, const int* in_sizes, int n_in,
                              void* d_out, int out_size, void* d_ws, size_t ws_size,
                              hipStream_t stream) {
    const float* x      = (const float*)d_in[0];
    const float* c      = (const float*)d_in[1];
    const float* w_mod  = (const float*)d_in[2];
    const float* b_mod  = (const float*)d_in[3];
    const float* w_qkv  = (const float*)d_in[4];
    const float* b_qkv  = (const float*)d_in[5];
    const float* g_q    = (const float*)d_in[6];
    const float* g_k    = (const float*)d_in[7];
    const float* w_proj = (const float*)d_in[8];
    const float* b_proj = (const float*)d_in[9];
    const float* w1     = (const float*)d_in[10];
    const float* b1     = (const float*)d_in[11];
    const float* w2     = (const float*)d_in[12];
    const float* b2     = (const float*)d_in[13];
    float* out = (float*)d_out;   // f32; also serves as x1 (residual after attn branch)

    // ---- workspace layout (runtime-sized, chunked row pipeline) ----
    char* ws = (char*)d_ws;
    size_t off = 0;
    auto alloc = [&](size_t bytes) { void* p = ws + off; off += (bytes + 255) & ~(size_t)255; return p; };
    float* modb  = (float*)alloc((size_t)NB*H6*4);
    bf16* wqkvT  = (bf16*)alloc((size_t)H3*H*2);
    bf16* wprojT = (bf16*)alloc((size_t)H*H*2);
    bf16* w1T    = (bf16*)alloc((size_t)MLPD*H*2);
    bf16* w2T    = (bf16*)alloc((size_t)H*MLPD*2);
    const size_t pers = off;

    // per-row chunk bytes: R1 (qkv|o|h overlay) = 9216, R2 (qln+kln+vt | xn overlay) = 8704
    int nchunk = 4;
    while (nchunk < 16 && pers + (size_t)(ROWS/nchunk)*(9216+8704) > ws_size) nchunk <<= 1;
    const int Rc = ROWS / nchunk;       // rows per chunk (multiple of 1024)
    const int Bc = NB / nchunk;         // batches per chunk

    char* R1 = ws + pers;                       // Rc*9216 bytes
    char* R2 = R1 + (size_t)Rc*9216;            // Rc*8704 bytes
    bf16* qkvc = (bf16*)R1;                     // Rc*3456 elems, live: qkv-gemm -> qk_ln/v_t
    bf16* oc   = (bf16*)R1;                     // Rc*1152, live: attn -> proj
    bf16* hc   = (bf16*)R1;                     // Rc*4608, live: mlp1 -> mlp2
    bf16* xnc  = (bf16*)R2;                     // Rc*1152, live: ln -> gemm (twice)
    bf16* qlnc = (bf16*)R2;                     // Bc*16*1024*96
    bf16* klnc = (bf16*)(R2 + (size_t)Rc*3072);
    bf16* vtc  = (bf16*)(R2 + (size_t)Rc*6144); // Bc*16*80*1024
    float* modp = (float*)R1;                   // mod partials (KSPLIT*NB*H6*4 = 7.1MB <= R1 9.4MB),
                                                // dead before first chunk kernel writes R1

    // ---- setup (once) ----
    mod_partial_kernel<<<dim3(H6/256, KSPLIT), 256, 0, stream>>>(c, w_mod, modp);
    mod_reduce_kernel<<<dim3(NB*H6/256), 256, 0, stream>>>(modp, b_mod, modb);
    transpose_kernel<<<dim3(H3/32,  H/32),   256, 0, stream>>>(w_qkv,  wqkvT,  H,    H3);
    transpose_kernel<<<dim3(H/32,   H/32),   256, 0, stream>>>(w_proj, wprojT, H,    H);
    transpose_kernel<<<dim3(MLPD/32,H/32),   256, 0, stream>>>(w1,     w1T,    H,    MLPD);
    transpose_kernel<<<dim3(H/32,   MLPD/32),256, 0, stream>>>(w2,     w2T,    MLPD, H);

    // ---- chunked pipeline ----
    for (int ci = 0; ci < nchunk; ++ci) {
        const int row0 = ci * Rc;
        // xn = LN(x)*(1+sc_msa)+sh_msa
        ln_mod_kernel<<<dim3(Rc), 256, 0, stream>>>(x, modb, 0, H, xnc, row0);
        // qkv = xn @ w_qkv + b_qkv
        gemm_bt<0><<<dim3(H3/128, Rc/128), 256, 0, stream>>>(xnc, wqkvT, b_qkv, nullptr, nullptr, qkvc, nullptr, Rc, H3, H, 0);
        // q/k layernorm (padded 96), v transpose
        qk_ln_kernel<<<dim3(Bc*NHEAD*NTOK/4), 256, 0, stream>>>(qkvc, g_q, g_k, qlnc, klnc);
        v_transpose_kernel<<<dim3(NTOK/64, NHEAD, Bc), 256, 0, stream>>>(qkvc, vtc);
        // attention (1D grid, XCD-aware bh mapping; 8 waves: 4 q-groups x 2 kv halves)
        attn_kernel<<<dim3(256*Bc), 512, 0, stream>>>(qlnc, klnc, vtc, oc, Bc);
        // x1 = x + g_msa*(o@w_proj+b_proj)   -> f32 in d_out
        gemm_bt<2><<<dim3(H/128, Rc/128), 256, 0, stream>>>(oc, wprojT, b_proj, x, modb + 2*H, nullptr, out, Rc, H, H, row0);
        // xn2 = LN(x1)*(1+sc_mlp)+sh_mlp
        ln_mod_kernel<<<dim3(Rc), 256, 0, stream>>>(out, modb, 3*H, 4*H, xnc, row0);
        // h = gelu(xn2@w1+b1)
        gemm_bt<1><<<dim3(MLPD/128, Rc/128), 256, 0, stream>>>(xnc, w1T, b1, nullptr, nullptr, hc, nullptr, Rc, MLPD, H, 0);
        // out = x1 + g_mlp*(h@w2+b2)   (f32, in-place residual)
        gemm_bt<2><<<dim3(H/128, Rc/128), 256, 0, stream>>>(hc, w2T, b2, out, modb + 5*H, nullptr, out, Rc, H, MLPD, row0);
    }
}

// Round 5
// 1879.946 us; speedup vs baseline: 1.1104x; 1.1104x over previous
//
#include <hip/hip_runtime.h>
#include <hip/hip_bf16.h>

#define H     1152
#define H3    3456
#define H6    6912
#define NTOK  1024
#define NB    16
#define NHEAD 16
#define HDIM  72
#define MLPD  4608
#define ROWS  (NB*NTOK)   // 16384
#define KSPLIT 16         // mod_kernel k-split (1152/16 = 72)

typedef __hip_bfloat16 bf16;
typedef float f32x4 __attribute__((ext_vector_type(4)));
typedef __bf16 bf16x8 __attribute__((ext_vector_type(8)));
typedef const __attribute__((address_space(1))) void* gptr_as1;
typedef __attribute__((address_space(3))) void* lptr_as3;

__device__ __forceinline__ float b2f(bf16 v){ return __bfloat162float(v); }
__device__ __forceinline__ bf16  f2b(float v){ return __float2bfloat16(v); }
__device__ __forceinline__ unsigned short f2bu(float v){ return __builtin_bit_cast(unsigned short, __float2bfloat16(v)); }

// ---- DPP 16-lane (row) butterfly reductions: VALU-pipe, no ds_swizzle ----
template<int CTRL>
__device__ __forceinline__ float fdpp(float x) {
    int xi = __float_as_int(x);
    int r = __builtin_amdgcn_update_dpp(xi, xi, CTRL, 0xF, 0xF, true);
    return __int_as_float(r);
}
__device__ __forceinline__ float rowmax16(float x) {
    x = fmaxf(x, fdpp<0xB1>(x));    // quad_perm [1,0,3,2]
    x = fmaxf(x, fdpp<0x4E>(x));    // quad_perm [2,3,0,1]
    x = fmaxf(x, fdpp<0x141>(x));   // row_half_mirror
    x = fmaxf(x, fdpp<0x140>(x));   // row_mirror
    return x;
}
__device__ __forceinline__ float rowsum16(float x) {
    x += fdpp<0xB1>(x);
    x += fdpp<0x4E>(x);
    x += fdpp<0x141>(x);
    x += fdpp<0x140>(x);
    return x;
}

// ---------------- mod stage 1 ----------------
__global__ __launch_bounds__(256) void mod_partial_kernel(const float* __restrict__ c,
                                                          const float* __restrict__ w_mod,
                                                          float* __restrict__ partial) {
    const int ks = blockIdx.y;
    const int k0 = ks * (H/KSPLIT);
    __shared__ float sw[NB*(H/KSPLIT)];
    for (int i = threadIdx.x; i < NB*(H/KSPLIT); i += 256) {
        int b = i/(H/KSPLIT), k = i - b*(H/KSPLIT);
        float cv = c[b*H + k0 + k];
        sw[i] = cv / (1.f + __expf(-cv));
    }
    __syncthreads();
    const int col = blockIdx.x*256 + threadIdx.x;   // H6 = 27*256
    float acc[NB];
    #pragma unroll
    for (int b = 0; b < NB; ++b) acc[b] = 0.f;
    for (int k = 0; k < H/KSPLIT; ++k) {
        float wv = w_mod[(long)(k0+k)*H6 + col];
        #pragma unroll
        for (int b = 0; b < NB; ++b) acc[b] += sw[b*(H/KSPLIT)+k] * wv;
    }
    #pragma unroll
    for (int b = 0; b < NB; ++b) partial[((long)ks*NB + b)*H6 + col] = acc[b];
}

// ---------------- mod stage 2 ----------------
__global__ __launch_bounds__(256) void mod_reduce_kernel(const float* __restrict__ partial,
                                                         const float* __restrict__ b_mod,
                                                         float* __restrict__ mod) {
    const int idx = blockIdx.x*256 + threadIdx.x;   // NB*H6 = 432*256
    const int col = idx % H6;
    float s = b_mod[col];
    #pragma unroll
    for (int ks = 0; ks < KSPLIT; ++ks) s += partial[(long)ks*NB*H6 + idx];
    mod[idx] = s;
}

// ---------------- row LN + adaLN modulate ----------------
__global__ __launch_bounds__(256) void ln_mod_kernel(const float* __restrict__ xin,
                                                     const float* __restrict__ mod,
                                                     int sh_off, int sc_off,
                                                     bf16* __restrict__ out,
                                                     int row0) {
    const int lrow = blockIdx.x;
    const long grow = (long)row0 + lrow;
    const int b = (int)(grow >> 10);
    const int tid = threadIdx.x;
    const long ibase = grow * H;
    const long obase = (long)lrow * H;
    __shared__ float sred[8];
    float vals[5];
    float sum = 0.f, sq = 0.f;
    #pragma unroll
    for (int i = 0; i < 5; ++i) {
        int cidx = i*256 + tid;
        float v = 0.f;
        if (cidx < H) v = xin[ibase+cidx];
        vals[i] = v; sum += v; sq += v*v;
    }
    #pragma unroll
    for (int off = 32; off > 0; off >>= 1) { sum += __shfl_down(sum, off); sq += __shfl_down(sq, off); }
    int wave = tid >> 6, lane = tid & 63;
    if (lane == 0) { sred[wave] = sum; sred[4+wave] = sq; }
    __syncthreads();
    if (tid == 0) {
        sred[0] = sred[0]+sred[1]+sred[2]+sred[3];
        sred[4] = sred[4]+sred[5]+sred[6]+sred[7];
    }
    __syncthreads();
    float mean = sred[0] * (1.f/H);
    float var  = sred[4] * (1.f/H) - mean*mean;
    float rstd = rsqrtf(var + 1e-6f);
    const float* mrow = mod + b*H6;
    #pragma unroll
    for (int i = 0; i < 5; ++i) {
        int cidx = i*256 + tid;
        if (cidx < H) {
            float y = (vals[i]-mean)*rstd;
            out[obase+cidx] = f2b(y * (1.f + mrow[sc_off+cidx]) + mrow[sh_off+cidx]);
        }
    }
}

// ---------------- f32 -> bf16 transpose ----------------
__global__ __launch_bounds__(256) void transpose_kernel(const float* __restrict__ in,
                                                        bf16* __restrict__ out, int R, int C) {
    __shared__ bf16 tile[32][33];
    int c0 = blockIdx.x*32, r0 = blockIdx.y*32;
    int tx = threadIdx.x & 31, ty = threadIdx.x >> 5;
    for (int j = ty; j < 32; j += 8) tile[j][tx] = f2b(in[(long)(r0+j)*C + c0 + tx]);
    __syncthreads();
    for (int j = ty; j < 32; j += 8) out[(long)(c0+j)*R + r0 + tx] = tile[tx][j];
}

// ---------------- m97-style GEMM ----------------
template<int EPI>
__global__ __launch_bounds__(256) void gemm_bt(const bf16* __restrict__ A, const bf16* __restrict__ BT,
                                               const float* __restrict__ bias,
                                               const float* __restrict__ res, const float* __restrict__ gate,
                                               bf16* __restrict__ C, float* __restrict__ Cf,
                                               int M, int N, int K, int row0) {
    __shared__ __align__(16) bf16 As[128*64];
    __shared__ __align__(16) bf16 Bs[128*64];
    const int tid  = threadIdx.x;
    const int wave = tid >> 6, lane = tid & 63;
    const int wm = wave & 1, wn = wave >> 1;
    const int col = lane & 15, quad = lane >> 4;
    f32x4 acc[4][4];
    #pragma unroll
    for (int i = 0; i < 4; ++i)
        #pragma unroll
        for (int j = 0; j < 4; ++j) acc[i][j] = (f32x4){0.f,0.f,0.f,0.f};

    const long arow0 = (long)blockIdx.y * 128;
    const long brow0 = (long)blockIdx.x * 128;
    const int  srow  = tid >> 3;
    const int  scol  = (tid & 7) * 8;
    const bf16* Ag = A + (arow0 + srow)*(long)K + scol;
    const bf16* Bg = BT + (brow0 + srow)*(long)K + scol;
    bf16* Asl = As + tid*8;
    bf16* Bsl = Bs + tid*8;

    for (int k0 = 0; k0 < K; k0 += 64) {
        __syncthreads();
        #pragma unroll
        for (int i = 0; i < 4; ++i) {
            __builtin_amdgcn_global_load_lds((gptr_as1)(Ag + (long)i*32*K + k0), (lptr_as3)(Asl + i*2048), 16, 0, 0);
            __builtin_amdgcn_global_load_lds((gptr_as1)(Bg + (long)i*32*K + k0), (lptr_as3)(Bsl + i*2048), 16, 0, 0);
        }
        __syncthreads();
        #pragma unroll
        for (int kk = 0; kk < 64; kk += 32) {
            bf16x8 af[4], bfr[4];
            #pragma unroll
            for (int mt = 0; mt < 4; ++mt) af[mt]  = *(const bf16x8*)&As[(wm*64+mt*16+col)*64 + kk + quad*8];
            #pragma unroll
            for (int nt = 0; nt < 4; ++nt) bfr[nt] = *(const bf16x8*)&Bs[(wn*64+nt*16+col)*64 + kk + quad*8];
            #pragma unroll
            for (int mt = 0; mt < 4; ++mt)
                #pragma unroll
                for (int nt = 0; nt < 4; ++nt)
                    acc[mt][nt] = __builtin_amdgcn_mfma_f32_16x16x32_bf16(af[mt], bfr[nt], acc[mt][nt], 0, 0, 0);
        }
    }

    #pragma unroll
    for (int mt = 0; mt < 4; ++mt) {
        #pragma unroll
        for (int nt = 0; nt < 4; ++nt) {
            const int colg = (int)brow0 + wn*64 + nt*16 + col;
            const float bv = bias[colg];
            #pragma unroll
            for (int r = 0; r < 4; ++r) {
                const long rowg = arow0 + wm*64 + mt*16 + quad*4 + r;
                float v = acc[mt][nt][r] + bv;
                if (EPI == 1) {
                    float u = 0.7978845608028654f*(v + 0.044715f*v*v*v);
                    v = v / (1.f + exp2f(-2.885390081777927f*u));
                    C[rowg*(long)N + colg] = f2b(v);
                } else if (EPI == 2) {
                    const long grow = row0 + rowg;
                    float g = gate[(int)(grow>>10)*H6 + colg];
                    Cf[grow*(long)N + colg] = res[grow*(long)N + colg] + g*v;
                } else {
                    C[rowg*(long)N + colg] = f2b(v);
                }
            }
        }
    }
}

// ---------------- per-head LN of q (row-major dst [bh][n][96]) ----------------
__device__ __forceinline__ void ln72q(const bf16* __restrict__ src, const float* __restrict__ gw,
                                      float scale, bf16* __restrict__ dst, int lane) {
    const int i1 = 64 + (lane & 7);
    float e0 = b2f(src[lane]);
    float e1 = (lane < 8) ? b2f(src[i1]) : 0.f;
    float s = e0 + e1;
    #pragma unroll
    for (int off = 32; off > 0; off >>= 1) s += __shfl_xor(s, off);
    float mean = s * (1.f/72.f);
    float d0 = e0 - mean;
    float d1 = (lane < 8) ? (e1 - mean) : 0.f;
    float sq = d0*d0 + d1*d1;
    #pragma unroll
    for (int off = 32; off > 0; off >>= 1) sq += __shfl_xor(sq, off);
    float rstd = rsqrtf(sq*(1.f/72.f) + 1e-6f);
    dst[lane] = f2b(d0*rstd*gw[lane]*scale);
    if (lane < 32) {
        float y1 = (lane < 8) ? d1*rstd*gw[i1]*scale : 0.f;
        dst[64+lane] = f2b(y1);
    }
}

// ---------------- per-head LN of k -> fragment-major dst ----------------
// K fragment layout per bh: [kvb16(64)][ks(3)][lane(64)][e(8)] bf16  (98304 elems = 192KB)
// element (token n, dim d): kvb=n>>4, ks=d>>5, quad=(d&31)>>3, e=d&7, lane=quad*16+(n&15)
__device__ __forceinline__ void ln72k(const bf16* __restrict__ src, const float* __restrict__ gw,
                                      bf16* __restrict__ kb, int n, int lane) {
    const int i1 = 64 + (lane & 7);
    float e0 = b2f(src[lane]);
    float e1 = (lane < 8) ? b2f(src[i1]) : 0.f;
    float s = e0 + e1;
    #pragma unroll
    for (int off = 32; off > 0; off >>= 1) s += __shfl_xor(s, off);
    float mean = s * (1.f/72.f);
    float d0 = e0 - mean;
    float d1 = (lane < 8) ? (e1 - mean) : 0.f;
    float sq = d0*d0 + d1*d1;
    #pragma unroll
    for (int off = 32; off > 0; off >>= 1) sq += __shfl_xor(sq, off);
    float rstd = rsqrtf(sq*(1.f/72.f) + 1e-6f);
    const int kvb = n >> 4, nc = n & 15;
    // d = lane (0..63): ks = lane>>5, quad = (lane&31)>>3, e = lane&7
    {
        int off1 = ((kvb*3 + (lane>>5))<<9) + ((((lane&31)>>3)<<4) + nc)*8 + (lane&7);
        kb[off1] = f2b(d0*rstd*gw[lane]);
    }
    // d = 64+lane (lane<32): ks=2, quad = lane>>3, e = lane&7 (zeros for d>=72)
    if (lane < 32) {
        float y1 = (lane < 8) ? d1*rstd*gw[i1] : 0.f;
        int off2 = ((kvb*3 + 2)<<9) + (((lane>>3)<<4) + nc)*8 + (lane&7);
        kb[off2] = f2b(y1);
    }
}

__global__ __launch_bounds__(256) void qk_ln_kernel(const bf16* __restrict__ qkv,  // chunk-local
                                                    const float* __restrict__ g_q, const float* __restrict__ g_k,
                                                    bf16* __restrict__ qln, bf16* __restrict__ kln) {
    const int wave = threadIdx.x >> 6, lane = threadIdx.x & 63;
    const long g  = (long)blockIdx.x*4 + wave;     // < Bc*NHEAD*NTOK
    const int  n  = (int)(g & 1023);
    const long bh = g >> 10;                        // local b*16 + h
    const int  h  = (int)(bh & 15);
    const int  b  = (int)(bh >> 4);
    const bf16* src = qkv + ((long)b*NTOK + n)*H3 + h*HDIM;
    // q scale = HD^-0.5 * log2(e)  (softmax computed in exp2 domain)
    ln72q(src,     g_q, 0.11785113019775793f * 1.4426950408889634f, qln + (bh*NTOK + n)*96, lane);
    ln72k(src + H, g_k, kln + bh*98304, n, lane);
}

// ---------------- V -> fragment-major VT ----------------
// layout per bh: [kvt(16)][hv(2)][nt(5)][lane(64)][e(8)] bf16 (81920 elems = 160KB)
// element: pos = hv*32 + (lane>>4)*8 + e; kv_local = (pos&3)*16 + (pos>>2); d = nt*16 + (lane&15)
__global__ __launch_bounds__(256) void v_transpose_kernel(const bf16* __restrict__ qkv, bf16* __restrict__ vt) {
    const int n0 = blockIdx.x*64;                  // kvt = blockIdx.x
    const int h = blockIdx.y, b = blockIdx.z;      // b local
    __shared__ bf16 tile[64][80];
    const long srcbase = ((long)b*NTOK + n0)*H3 + 2*H + h*HDIM;
    for (int idx = threadIdx.x; idx < 64*72; idx += 256) {
        int n = idx/72, d = idx - n*72;
        tile[n][d] = qkv[srcbase + (long)n*H3 + d];
    }
    for (int idx = threadIdx.x; idx < 64*8; idx += 256) {
        int n = idx >> 3, d = idx & 7;
        tile[n][72+d] = f2b(0.f);
    }
    __syncthreads();
    const long bh = (long)(b*NHEAD + h);
    bf16* dst = vt + (bh*16 + blockIdx.x)*5120;
    for (int o = threadIdx.x; o < 5120; o += 256) {
        int hv5 = o >> 9;                  // 0..9 = hv*5+nt
        int hv = (hv5 >= 5) ? 1 : 0;
        int nt = hv5 - hv*5;
        int lane = (o >> 3) & 63;
        int e = o & 7;
        int pos = hv*32 + ((lane>>4)<<3) + e;
        int kv_local = ((pos & 3) << 4) + (pos >> 2);
        int d = (nt << 4) + (lane & 15);
        dst[o] = tile[kv_local][d];
        (void)nt;
    }
}

// ---------------- flash attention, 2-way KV split, KVBLK=64, XCD-aware bh mapping ----------------
// fragment-major K/V (all global loads = base + lane*16B, fully coalesced)
// P stored packed: row q, position pos=col*4+j (kv = j*16+col); V layout compensates the permutation.
#define PSTR 72
__global__ __launch_bounds__(512) void attn_kernel(const bf16* __restrict__ qln, const bf16* __restrict__ kln,
                                                   const bf16* __restrict__ vt, bf16* __restrict__ o,
                                                   int Bc) {
    const int tid = threadIdx.x;
    const int wave = tid >> 6, lane = tid & 63;
    const int qg = wave & 3, half = wave >> 2;
    const int col = lane & 15, quad = lane >> 4;

    // XCD-aware decomposition of linear block id
    const int L = blockIdx.x;
    const int P_ = 2*Bc;                 // bh per XCD = 16*Bc/8
    const int c8 = L & 7;
    const int j  = L >> 3;               // [0, 32*Bc)
    const int bh_l = c8*P_ + (j % P_);   // [0, 16*Bc)
    const int qt   = j / P_;             // [0, 16)
    const int b = bh_l >> 4, h = bh_l & 15;
    const long bh = bh_l;

    const int q0 = qt*64 + qg*16;
    const bf16* qb = qln + bh*NTOK*96;
    const bf16* kb = kln + bh*98304;
    const bf16* vb = vt  + bh*81920;

    // LDS: [0,18432) = 8 per-wave P tiles (16 rows x stride 72 bf16 = 2304B each)
    // merge (after sync): O [0,20480) f32x4; M [20480,24576); L [24576,28672)
    __shared__ __align__(16) char smraw[28672];
    bf16* pw = (bf16*)smraw + wave*(16*PSTR);
    f32x4* Osm = (f32x4*)smraw;
    f32x4* Msm = (f32x4*)(smraw + 20480);
    f32x4* Lsm = (f32x4*)(smraw + 24576);

    bf16x8 qf[3];
    #pragma unroll
    for (int ks = 0; ks < 3; ++ks) qf[ks] = *(const bf16x8*)&qb[(q0+col)*96 + ks*32 + quad*8];

    f32x4 oacc[5];
    #pragma unroll
    for (int i = 0; i < 5; ++i) oacc[i] = (f32x4){0.f,0.f,0.f,0.f};
    float mrow[4], lrow[4];
    #pragma unroll
    for (int r = 0; r < 4; ++r) { mrow[r] = -1e30f; lrow[r] = 0.f; }

    const int kvbeg = half*512, kvend = kvbeg + 512;
    for (int kv0 = kvbeg; kv0 < kvend; kv0 += 64) {
        const int kvb16 = kv0 >> 4;
        const int kvt   = kv0 >> 6;
        // ---- QK^T: S[16q x 64k], fragment-major K loads (coalesced) ----
        f32x4 s[4];
        #pragma unroll
        for (int j4 = 0; j4 < 4; ++j4) s[j4] = (f32x4){0.f,0.f,0.f,0.f};
        #pragma unroll
        for (int j4 = 0; j4 < 4; ++j4)
            #pragma unroll
            for (int ks = 0; ks < 3; ++ks) {
                bf16x8 kf = *(const bf16x8*)&kb[(((kvb16 + j4)*3 + ks)<<9) + lane*8];
                s[j4] = __builtin_amdgcn_mfma_f32_16x16x32_bf16(qf[ks], kf, s[j4], 0, 0, 0);
            }
        // ---- online softmax (exp2 domain), DPP reductions, packed P stores ----
        float alpha[4];
        #pragma unroll
        for (int r = 0; r < 4; ++r) {
            float tm = fmaxf(fmaxf(s[0][r], s[1][r]), fmaxf(s[2][r], s[3][r]));
            tm = rowmax16(tm);
            float mn = fmaxf(mrow[r], tm);
            alpha[r] = exp2f(mrow[r] - mn);
            float p0 = exp2f(s[0][r] - mn);
            float p1 = exp2f(s[1][r] - mn);
            float p2 = exp2f(s[2][r] - mn);
            float p3 = exp2f(s[3][r] - mn);
            float ts = rowsum16((p0+p1)+(p2+p3));
            lrow[r] = lrow[r]*alpha[r] + ts;
            mrow[r] = mn;
            const int prow = quad*4 + r;
            // packed store: positions col*4+{0,1,2,3} <-> kv j*16+col
            unsigned int lo = (unsigned int)f2bu(p0) | ((unsigned int)f2bu(p1) << 16);
            unsigned int hi = (unsigned int)f2bu(p2) | ((unsigned int)f2bu(p3) << 16);
            unsigned long long pk = (unsigned long long)lo | ((unsigned long long)hi << 32);
            *(unsigned long long*)&pw[prow*PSTR + col*4] = pk;
        }
        // ---- deferred rescale: alpha==1.0 exactly when row max unchanged ----
        if (__any(alpha[0]+alpha[1]+alpha[2]+alpha[3] < 4.f)) {
            #pragma unroll
            for (int i = 0; i < 5; ++i)
                #pragma unroll
                for (int r = 0; r < 4; ++r) oacc[i][r] *= alpha[r];
        }
        // P read (DS pipe is in-order per wave; compiler inserts the counted lgkm wait)
        bf16x8 pf0 = *(const bf16x8*)&pw[col*PSTR + quad*8];
        bf16x8 pf1 = *(const bf16x8*)&pw[col*PSTR + 32 + quad*8];
        #pragma unroll
        for (int nt = 0; nt < 5; ++nt) {
            bf16x8 vf0 = *(const bf16x8*)&vb[((kvt*10 + nt)<<9) + lane*8];
            bf16x8 vf1 = *(const bf16x8*)&vb[((kvt*10 + 5 + nt)<<9) + lane*8];
            oacc[nt] = __builtin_amdgcn_mfma_f32_16x16x32_bf16(pf0, vf0, oacc[nt], 0, 0, 0);
            oacc[nt] = __builtin_amdgcn_mfma_f32_16x16x32_bf16(pf1, vf1, oacc[nt], 0, 0, 0);
        }
    }

    // ---- merge the two KV halves ----
    __syncthreads();   // all waves done with P tiles (merge buffers alias them)
    if (half) {
        f32x4 mv, lv;
        #pragma unroll
        for (int r = 0; r < 4; ++r) { mv[r] = mrow[r]; lv[r] = lrow[r]; }
        Msm[qg*64 + lane] = mv;
        Lsm[qg*64 + lane] = lv;
        #pragma unroll
        for (int nt = 0; nt < 5; ++nt) Osm[(qg*5 + nt)*64 + lane] = oacc[nt];
    }
    __syncthreads();
    if (!half) {
        f32x4 mB = Msm[qg*64 + lane];
        f32x4 lB = Lsm[qg*64 + lane];
        float aA[4], aB[4], inv[4];
        #pragma unroll
        for (int r = 0; r < 4; ++r) {
            float ms = fmaxf(mrow[r], mB[r]);
            aA[r] = exp2f(mrow[r] - ms);
            aB[r] = exp2f(mB[r] - ms);
            float ls = lrow[r]*aA[r] + lB[r]*aB[r];
            inv[r] = 1.f / ls;
        }
        #pragma unroll
        for (int nt = 0; nt < 5; ++nt) {
            f32x4 oB = Osm[(qg*5 + nt)*64 + lane];
            int d = nt*16 + col;
            if (d < HDIM) {
                #pragma unroll
                for (int r = 0; r < 4; ++r) {
                    int qrow = q0 + quad*4 + r;
                    o[((long)b*NTOK + qrow)*H + h*HDIM + d] = f2b((oacc[nt][r]*aA[r] + oB[r]*aB[r])*inv[r]);
                }
            }
        }
    }
}

extern "C" void kernel_launch(void* const* d_in, const int* in_sizes, int n_in,
                              void* d_out, int out_size, void* d_ws, size_t ws_size,
                              hipStream_t stream) {
    const float* x      = (const float*)d_in[0];
    const float* c      = (const float*)d_in[1];
    const float* w_mod  = (const float*)d_in[2];
    const float* b_mod  = (const float*)d_in[3];
    const float* w_qkv  = (const float*)d_in[4];
    const float* b_qkv  = (const float*)d_in[5];
    const float* g_q    = (const float*)d_in[6];
    const float* g_k    = (const float*)d_in[7];
    const float* w_proj = (const float*)d_in[8];
    const float* b_proj = (const float*)d_in[9];
    const float* w1     = (const float*)d_in[10];
    const float* b1     = (const float*)d_in[11];
    const float* w2     = (const float*)d_in[12];
    const float* b2     = (const float*)d_in[13];
    float* out = (float*)d_out;   // f32; also serves as x1 (residual after attn branch)

    // ---- workspace layout (runtime-sized, chunked row pipeline) ----
    char* ws = (char*)d_ws;
    size_t off = 0;
    auto alloc = [&](size_t bytes) { void* p = ws + off; off += (bytes + 255) & ~(size_t)255; return p; };
    float* modb  = (float*)alloc((size_t)NB*H6*4);
    bf16* wqkvT  = (bf16*)alloc((size_t)H3*H*2);
    bf16* wprojT = (bf16*)alloc((size_t)H*H*2);
    bf16* w1T    = (bf16*)alloc((size_t)MLPD*H*2);
    bf16* w2T    = (bf16*)alloc((size_t)H*MLPD*2);
    const size_t pers = off;

    // per-row chunk bytes: R1 (qkv|o|h overlay) = 9216, R2 (qln+kln+vt | xn overlay) = 8704
    int nchunk = 4;
    while (nchunk < 16 && pers + (size_t)(ROWS/nchunk)*(9216+8704) > ws_size) nchunk <<= 1;
    const int Rc = ROWS / nchunk;       // rows per chunk (multiple of 1024)
    const int Bc = NB / nchunk;         // batches per chunk

    char* R1 = ws + pers;                       // Rc*9216 bytes
    char* R2 = R1 + (size_t)Rc*9216;            // Rc*8704 bytes
    bf16* qkvc = (bf16*)R1;                     // Rc*3456 elems, live: qkv-gemm -> qk_ln/v_t
    bf16* oc   = (bf16*)R1;                     // Rc*1152, live: attn -> proj
    bf16* hc   = (bf16*)R1;                     // Rc*4608, live: mlp1 -> mlp2
    bf16* xnc  = (bf16*)R2;                     // Rc*1152, live: ln -> gemm (twice)
    bf16* qlnc = (bf16*)R2;                     // Bc*16*1024*96  (q row-major)
    bf16* klnc = (bf16*)(R2 + (size_t)Rc*3072); // Bc*16*98304 elems (K fragment-major, 192KB/bh)
    bf16* vtc  = (bf16*)(R2 + (size_t)Rc*6144); // Bc*16*81920 elems (V fragment-major, 160KB/bh)
    float* modp = (float*)R1;                   // mod partials (dead before first chunk kernel writes R1)

    // ---- setup (once) ----
    mod_partial_kernel<<<dim3(H6/256, KSPLIT), 256, 0, stream>>>(c, w_mod, modp);
    mod_reduce_kernel<<<dim3(NB*H6/256), 256, 0, stream>>>(modp, b_mod, modb);
    transpose_kernel<<<dim3(H3/32,  H/32),   256, 0, stream>>>(w_qkv,  wqkvT,  H,    H3);
    transpose_kernel<<<dim3(H/32,   H/32),   256, 0, stream>>>(w_proj, wprojT, H,    H);
    transpose_kernel<<<dim3(MLPD/32,H/32),   256, 0, stream>>>(w1,     w1T,    H,    MLPD);
    transpose_kernel<<<dim3(H/32,   MLPD/32),256, 0, stream>>>(w2,     w2T,    MLPD, H);

    // ---- chunked pipeline ----
    for (int ci = 0; ci < nchunk; ++ci) {
        const int row0 = ci * Rc;
        // xn = LN(x)*(1+sc_msa)+sh_msa
        ln_mod_kernel<<<dim3(Rc), 256, 0, stream>>>(x, modb, 0, H, xnc, row0);
        // qkv = xn @ w_qkv + b_qkv
        gemm_bt<0><<<dim3(H3/128, Rc/128), 256, 0, stream>>>(xnc, wqkvT, b_qkv, nullptr, nullptr, qkvc, nullptr, Rc, H3, H, 0);
        // q/k layernorm (q row-major, k fragment-major), v fragment-major transpose
        qk_ln_kernel<<<dim3(Bc*NHEAD*NTOK/4), 256, 0, stream>>>(qkvc, g_q, g_k, qlnc, klnc);
        v_transpose_kernel<<<dim3(NTOK/64, NHEAD, Bc), 256, 0, stream>>>(qkvc, vtc);
        // attention (1D grid, XCD-aware bh mapping; 8 waves: 4 q-groups x 2 kv halves)
        attn_kernel<<<dim3(256*Bc), 512, 0, stream>>>(qlnc, klnc, vtc, oc, Bc);
        // x1 = x + g_msa*(o@w_proj+b_proj)   -> f32 in d_out
        gemm_bt<2><<<dim3(H/128, Rc/128), 256, 0, stream>>>(oc, wprojT, b_proj, x, modb + 2*H, nullptr, out, Rc, H, H, row0);
        // xn2 = LN(x1)*(1+sc_mlp)+sh_mlp
        ln_mod_kernel<<<dim3(Rc), 256, 0, stream>>>(out, modb, 3*H, 4*H, xnc, row0);
        // h = gelu(xn2@w1+b1)
        gemm_bt<1><<<dim3(MLPD/128, Rc/128), 256, 0, stream>>>(xnc, w1T, b1, nullptr, nullptr, hc, nullptr, Rc, MLPD, H, 0);
        // out = x1 + g_mlp*(h@w2+b2)   (f32, in-place residual)
        gemm_bt<2><<<dim3(H/128, Rc/128), 256, 0, stream>>>(hc, w2T, b2, out, modb + 5*H, nullptr, out, Rc, H, MLPD, row0);
    }
}

// Round 6
// 1557.108 us; speedup vs baseline: 1.3406x; 1.2073x over previous
//
#include <hip/hip_runtime.h>
#include <hip/hip_bf16.h>

#define H     1152
#define H3    3456
#define H6    6912
#define NTOK  1024
#define NB    16
#define NHEAD 16
#define HDIM  72
#define MLPD  4608
#define ROWS  (NB*NTOK)   // 16384
#define KSPLIT 16         // mod_kernel k-split (1152/16 = 72)

typedef __hip_bfloat16 bf16;
typedef float f32x4 __attribute__((ext_vector_type(4)));
typedef __bf16 bf16x8 __attribute__((ext_vector_type(8)));
typedef const __attribute__((address_space(1))) void* gptr_as1;
typedef __attribute__((address_space(3))) void* lptr_as3;

__device__ __forceinline__ float b2f(bf16 v){ return __bfloat162float(v); }
__device__ __forceinline__ bf16  f2b(float v){ return __float2bfloat16(v); }
__device__ __forceinline__ unsigned short f2bu(float v){ return __builtin_bit_cast(unsigned short, __float2bfloat16(v)); }

// ---- DPP 16-lane (row) butterfly reductions: VALU-pipe, no ds_swizzle ----
template<int CTRL>
__device__ __forceinline__ float fdpp(float x) {
    int xi = __float_as_int(x);
    int r = __builtin_amdgcn_update_dpp(xi, xi, CTRL, 0xF, 0xF, true);
    return __int_as_float(r);
}
__device__ __forceinline__ float rowmax16(float x) {
    x = fmaxf(x, fdpp<0xB1>(x));    // quad_perm [1,0,3,2]
    x = fmaxf(x, fdpp<0x4E>(x));    // quad_perm [2,3,0,1]
    x = fmaxf(x, fdpp<0x141>(x));   // row_half_mirror
    x = fmaxf(x, fdpp<0x140>(x));   // row_mirror
    return x;
}
__device__ __forceinline__ float rowsum16(float x) {
    x += fdpp<0xB1>(x);
    x += fdpp<0x4E>(x);
    x += fdpp<0x141>(x);
    x += fdpp<0x140>(x);
    return x;
}

// ---------------- mod stage 1 ----------------
__global__ __launch_bounds__(256) void mod_partial_kernel(const float* __restrict__ c,
                                                          const float* __restrict__ w_mod,
                                                          float* __restrict__ partial) {
    const int ks = blockIdx.y;
    const int k0 = ks * (H/KSPLIT);
    __shared__ float sw[NB*(H/KSPLIT)];
    for (int i = threadIdx.x; i < NB*(H/KSPLIT); i += 256) {
        int b = i/(H/KSPLIT), k = i - b*(H/KSPLIT);
        float cv = c[b*H + k0 + k];
        sw[i] = cv / (1.f + __expf(-cv));
    }
    __syncthreads();
    const int col = blockIdx.x*256 + threadIdx.x;   // H6 = 27*256
    float acc[NB];
    #pragma unroll
    for (int b = 0; b < NB; ++b) acc[b] = 0.f;
    for (int k = 0; k < H/KSPLIT; ++k) {
        float wv = w_mod[(long)(k0+k)*H6 + col];
        #pragma unroll
        for (int b = 0; b < NB; ++b) acc[b] += sw[b*(H/KSPLIT)+k] * wv;
    }
    #pragma unroll
    for (int b = 0; b < NB; ++b) partial[((long)ks*NB + b)*H6 + col] = acc[b];
}

// ---------------- mod stage 2 ----------------
__global__ __launch_bounds__(256) void mod_reduce_kernel(const float* __restrict__ partial,
                                                         const float* __restrict__ b_mod,
                                                         float* __restrict__ mod) {
    const int idx = blockIdx.x*256 + threadIdx.x;   // NB*H6 = 432*256
    const int col = idx % H6;
    float s = b_mod[col];
    #pragma unroll
    for (int ks = 0; ks < KSPLIT; ++ks) s += partial[(long)ks*NB*H6 + idx];
    mod[idx] = s;
}

// ---------------- row LN + adaLN modulate ----------------
__global__ __launch_bounds__(256) void ln_mod_kernel(const float* __restrict__ xin,
                                                     const float* __restrict__ mod,
                                                     int sh_off, int sc_off,
                                                     bf16* __restrict__ out,
                                                     int row0) {
    const int lrow = blockIdx.x;
    const long grow = (long)row0 + lrow;
    const int b = (int)(grow >> 10);
    const int tid = threadIdx.x;
    const long ibase = grow * H;
    const long obase = (long)lrow * H;
    __shared__ float sred[8];
    float vals[5];
    float sum = 0.f, sq = 0.f;
    #pragma unroll
    for (int i = 0; i < 5; ++i) {
        int cidx = i*256 + tid;
        float v = 0.f;
        if (cidx < H) v = xin[ibase+cidx];
        vals[i] = v; sum += v; sq += v*v;
    }
    #pragma unroll
    for (int off = 32; off > 0; off >>= 1) { sum += __shfl_down(sum, off); sq += __shfl_down(sq, off); }
    int wave = tid >> 6, lane = tid & 63;
    if (lane == 0) { sred[wave] = sum; sred[4+wave] = sq; }
    __syncthreads();
    if (tid == 0) {
        sred[0] = sred[0]+sred[1]+sred[2]+sred[3];
        sred[4] = sred[4]+sred[5]+sred[6]+sred[7];
    }
    __syncthreads();
    float mean = sred[0] * (1.f/H);
    float var  = sred[4] * (1.f/H) - mean*mean;
    float rstd = rsqrtf(var + 1e-6f);
    const float* mrow = mod + b*H6;
    #pragma unroll
    for (int i = 0; i < 5; ++i) {
        int cidx = i*256 + tid;
        if (cidx < H) {
            float y = (vals[i]-mean)*rstd;
            out[obase+cidx] = f2b(y * (1.f + mrow[sc_off+cidx]) + mrow[sh_off+cidx]);
        }
    }
}

// ---------------- f32 -> bf16 transpose ----------------
__global__ __launch_bounds__(256) void transpose_kernel(const float* __restrict__ in,
                                                        bf16* __restrict__ out, int R, int C) {
    __shared__ bf16 tile[32][33];
    int c0 = blockIdx.x*32, r0 = blockIdx.y*32;
    int tx = threadIdx.x & 31, ty = threadIdx.x >> 5;
    for (int j = ty; j < 32; j += 8) tile[j][tx] = f2b(in[(long)(r0+j)*C + c0 + tx]);
    __syncthreads();
    for (int j = ty; j < 32; j += 8) out[(long)(c0+j)*R + r0 + tx] = tile[tx][j];
}

// ---------------- m97-style GEMM + T2 LDS swizzle + XCD-chunked 1D grid ----------------
// LDS layout: LDS[row][c] = X[row][c ^ ((row&7)*8)] (swizzle via pre-swizzled global source;
// global_load_lds dest stays linear). Reads XOR with (col&7)*8 -> canonical fragments, 2-way banks.
template<int EPI>
__global__ __launch_bounds__(256) void gemm_bt(const bf16* __restrict__ A, const bf16* __restrict__ BT,
                                               const float* __restrict__ bias,
                                               const float* __restrict__ res, const float* __restrict__ gate,
                                               bf16* __restrict__ C, float* __restrict__ Cf,
                                               int M, int N, int K, int row0) {
    __shared__ __align__(16) bf16 As[128*64];
    __shared__ __align__(16) bf16 Bs[128*64];
    const int tid  = threadIdx.x;
    const int wave = tid >> 6, lane = tid & 63;
    const int wm = wave & 1, wn = wave >> 1;
    const int col = lane & 15, quad = lane >> 4;

    // bijective XCD-chunked swizzle of 1D grid; bx-fast within chunk (A-panel co-timed on one XCD)
    const int nbx = N >> 7;
    const int nwg = gridDim.x;
    const int L = blockIdx.x;
    const int l = ((nwg & 7) == 0) ? ((L & 7)*(nwg >> 3) + (L >> 3)) : L;
    const int bx = l % nbx, by = l / nbx;

    f32x4 acc[4][4];
    #pragma unroll
    for (int i = 0; i < 4; ++i)
        #pragma unroll
        for (int j = 0; j < 4; ++j) acc[i][j] = (f32x4){0.f,0.f,0.f,0.f};

    const long arow0 = (long)by * 128;
    const long brow0 = (long)bx * 128;
    const int  srow  = tid >> 3;
    const int  scol  = (tid & 7) * 8;
    const int  scolsw = scol ^ ((srow & 7) * 8);   // pre-swizzled source col
    const bf16* Ag = A + (arow0 + srow)*(long)K + scolsw;
    const bf16* Bg = BT + (brow0 + srow)*(long)K + scolsw;
    bf16* Asl = As + tid*8;
    bf16* Bsl = Bs + tid*8;

    for (int k0 = 0; k0 < K; k0 += 64) {
        __syncthreads();
        #pragma unroll
        for (int i = 0; i < 4; ++i) {
            __builtin_amdgcn_global_load_lds((gptr_as1)(Ag + (long)i*32*K + k0), (lptr_as3)(Asl + i*2048), 16, 0, 0);
            __builtin_amdgcn_global_load_lds((gptr_as1)(Bg + (long)i*32*K + k0), (lptr_as3)(Bsl + i*2048), 16, 0, 0);
        }
        __syncthreads();
        const int xr = (col & 7) * 8;
        #pragma unroll
        for (int kk = 0; kk < 64; kk += 32) {
            bf16x8 af[4], bfr[4];
            #pragma unroll
            for (int mt = 0; mt < 4; ++mt) af[mt]  = *(const bf16x8*)&As[(wm*64+mt*16+col)*64 + ((kk + quad*8) ^ xr)];
            #pragma unroll
            for (int nt = 0; nt < 4; ++nt) bfr[nt] = *(const bf16x8*)&Bs[(wn*64+nt*16+col)*64 + ((kk + quad*8) ^ xr)];
            #pragma unroll
            for (int mt = 0; mt < 4; ++mt)
                #pragma unroll
                for (int nt = 0; nt < 4; ++nt)
                    acc[mt][nt] = __builtin_amdgcn_mfma_f32_16x16x32_bf16(af[mt], bfr[nt], acc[mt][nt], 0, 0, 0);
        }
    }

    #pragma unroll
    for (int mt = 0; mt < 4; ++mt) {
        #pragma unroll
        for (int nt = 0; nt < 4; ++nt) {
            const int colg = (int)brow0 + wn*64 + nt*16 + col;
            const float bv = bias[colg];
            #pragma unroll
            for (int r = 0; r < 4; ++r) {
                const long rowg = arow0 + wm*64 + mt*16 + quad*4 + r;
                float v = acc[mt][nt][r] + bv;
                if (EPI == 1) {
                    float u = 0.7978845608028654f*(v + 0.044715f*v*v*v);
                    v = v / (1.f + exp2f(-2.885390081777927f*u));
                    C[rowg*(long)N + colg] = f2b(v);
                } else if (EPI == 2) {
                    const long grow = row0 + rowg;
                    float g = gate[(int)(grow>>10)*H6 + colg];
                    Cf[grow*(long)N + colg] = res[grow*(long)N + colg] + g*v;
                } else {
                    C[rowg*(long)N + colg] = f2b(v);
                }
            }
        }
    }
}

// ---------------- per-head LN of q (row-major dst [bh][n][96]) ----------------
__device__ __forceinline__ void ln72q(const bf16* __restrict__ src, const float* __restrict__ gw,
                                      float scale, bf16* __restrict__ dst, int lane) {
    const int i1 = 64 + (lane & 7);
    float e0 = b2f(src[lane]);
    float e1 = (lane < 8) ? b2f(src[i1]) : 0.f;
    float s = e0 + e1;
    #pragma unroll
    for (int off = 32; off > 0; off >>= 1) s += __shfl_xor(s, off);
    float mean = s * (1.f/72.f);
    float d0 = e0 - mean;
    float d1 = (lane < 8) ? (e1 - mean) : 0.f;
    float sq = d0*d0 + d1*d1;
    #pragma unroll
    for (int off = 32; off > 0; off >>= 1) sq += __shfl_xor(sq, off);
    float rstd = rsqrtf(sq*(1.f/72.f) + 1e-6f);
    dst[lane] = f2b(d0*rstd*gw[lane]*scale);
    if (lane < 32) {
        float y1 = (lane < 8) ? d1*rstd*gw[i1]*scale : 0.f;
        dst[64+lane] = f2b(y1);
    }
}

// ---------------- per-head LN of k -> fragment-major dst ----------------
// K fragment layout per bh: [kvb16(64)][ks(3)][lane(64)][e(8)] bf16  (98304 elems = 192KB)
__device__ __forceinline__ void ln72k(const bf16* __restrict__ src, const float* __restrict__ gw,
                                      bf16* __restrict__ kb, int n, int lane) {
    const int i1 = 64 + (lane & 7);
    float e0 = b2f(src[lane]);
    float e1 = (lane < 8) ? b2f(src[i1]) : 0.f;
    float s = e0 + e1;
    #pragma unroll
    for (int off = 32; off > 0; off >>= 1) s += __shfl_xor(s, off);
    float mean = s * (1.f/72.f);
    float d0 = e0 - mean;
    float d1 = (lane < 8) ? (e1 - mean) : 0.f;
    float sq = d0*d0 + d1*d1;
    #pragma unroll
    for (int off = 32; off > 0; off >>= 1) sq += __shfl_xor(sq, off);
    float rstd = rsqrtf(sq*(1.f/72.f) + 1e-6f);
    const int kvb = n >> 4, nc = n & 15;
    {
        int off1 = ((kvb*3 + (lane>>5))<<9) + ((((lane&31)>>3)<<4) + nc)*8 + (lane&7);
        kb[off1] = f2b(d0*rstd*gw[lane]);
    }
    if (lane < 32) {
        float y1 = (lane < 8) ? d1*rstd*gw[i1] : 0.f;
        int off2 = ((kvb*3 + 2)<<9) + (((lane>>3)<<4) + nc)*8 + (lane&7);
        kb[off2] = f2b(y1);
    }
}

__global__ __launch_bounds__(256) void qk_ln_kernel(const bf16* __restrict__ qkv,  // chunk-local
                                                    const float* __restrict__ g_q, const float* __restrict__ g_k,
                                                    bf16* __restrict__ qln, bf16* __restrict__ kln) {
    const int wave = threadIdx.x >> 6, lane = threadIdx.x & 63;
    const long g  = (long)blockIdx.x*4 + wave;     // < Bc*NHEAD*NTOK
    const int  n  = (int)(g & 1023);
    const long bh = g >> 10;                        // local b*16 + h
    const int  h  = (int)(bh & 15);
    const int  b  = (int)(bh >> 4);
    const bf16* src = qkv + ((long)b*NTOK + n)*H3 + h*HDIM;
    // q scale = HD^-0.5 * log2(e)  (softmax computed in exp2 domain)
    ln72q(src,     g_q, 0.11785113019775793f * 1.4426950408889634f, qln + (bh*NTOK + n)*96, lane);
    ln72k(src + H, g_k, kln + bh*98304, n, lane);
}

// ---------------- V -> fragment-major VT ----------------
// layout per bh: [kvt(16)][hv(2)][nt(5)][lane(64)][e(8)] bf16 (81920 elems = 160KB)
__global__ __launch_bounds__(256) void v_transpose_kernel(const bf16* __restrict__ qkv, bf16* __restrict__ vt) {
    const int n0 = blockIdx.x*64;                  // kvt = blockIdx.x
    const int h = blockIdx.y, b = blockIdx.z;      // b local
    __shared__ bf16 tile[64][80];
    const long srcbase = ((long)b*NTOK + n0)*H3 + 2*H + h*HDIM;
    for (int idx = threadIdx.x; idx < 64*72; idx += 256) {
        int n = idx/72, d = idx - n*72;
        tile[n][d] = qkv[srcbase + (long)n*H3 + d];
    }
    for (int idx = threadIdx.x; idx < 64*8; idx += 256) {
        int n = idx >> 3, d = idx & 7;
        tile[n][72+d] = f2b(0.f);
    }
    __syncthreads();
    const long bh = (long)(b*NHEAD + h);
    bf16* dst = vt + (bh*16 + blockIdx.x)*5120;
    for (int o = threadIdx.x; o < 5120; o += 256) {
        int hv5 = o >> 9;                  // 0..9 = hv*5+nt
        int hv = (hv5 >= 5) ? 1 : 0;
        int nt = hv5 - hv*5;
        int lane = (o >> 3) & 63;
        int e = o & 7;
        int pos = hv*32 + ((lane>>4)<<3) + e;
        int kv_local = ((pos & 3) << 4) + (pos >> 2);
        int d = (nt << 4) + (lane & 15);
        dst[o] = tile[kv_local][d];
        (void)nt;
    }
}

// ---------------- flash attention, 2-way KV split, KVBLK=64, XCD-aware bh mapping ----------------
// fragment-major K/V (all global loads = base + lane*16B, fully coalesced)
// qt-major within XCD chunk: concurrent blocks share few bh -> K/V L2-resident at any Bc.
#define PSTR 72
__global__ __launch_bounds__(512) void attn_kernel(const bf16* __restrict__ qln, const bf16* __restrict__ kln,
                                                   const bf16* __restrict__ vt, bf16* __restrict__ o,
                                                   int Bc) {
    const int tid = threadIdx.x;
    const int wave = tid >> 6, lane = tid & 63;
    const int qg = wave & 3, half = wave >> 2;
    const int col = lane & 15, quad = lane >> 4;

    // XCD-aware decomposition of linear block id (qt fast within chunk)
    const int L = blockIdx.x;
    const int c8 = L & 7;
    const int j  = L >> 3;               // [0, 32*Bc)
    const int qt  = j & 15;
    const int bhi = j >> 4;              // [0, 2*Bc)
    const int bh_l = c8*(2*Bc) + bhi;    // [0, 16*Bc)
    const int b = bh_l >> 4, h = bh_l & 15;
    const long bh = bh_l;

    const int q0 = qt*64 + qg*16;
    const bf16* qb = qln + bh*NTOK*96;
    const bf16* kb = kln + bh*98304;
    const bf16* vb = vt  + bh*81920;

    // LDS: [0,18432) = 8 per-wave P tiles (16 rows x stride 72 bf16 = 2304B each)
    // merge (after sync): O [0,20480) f32x4; M [20480,24576); L [24576,28672)
    __shared__ __align__(16) char smraw[28672];
    bf16* pw = (bf16*)smraw + wave*(16*PSTR);
    f32x4* Osm = (f32x4*)smraw;
    f32x4* Msm = (f32x4*)(smraw + 20480);
    f32x4* Lsm = (f32x4*)(smraw + 24576);

    bf16x8 qf[3];
    #pragma unroll
    for (int ks = 0; ks < 3; ++ks) qf[ks] = *(const bf16x8*)&qb[(q0+col)*96 + ks*32 + quad*8];

    f32x4 oacc[5];
    #pragma unroll
    for (int i = 0; i < 5; ++i) oacc[i] = (f32x4){0.f,0.f,0.f,0.f};
    float mrow[4], lrow[4];
    #pragma unroll
    for (int r = 0; r < 4; ++r) { mrow[r] = -1e30f; lrow[r] = 0.f; }

    const int kvbeg = half*512, kvend = kvbeg + 512;
    for (int kv0 = kvbeg; kv0 < kvend; kv0 += 64) {
        const int kvb16 = kv0 >> 4;
        const int kvt   = kv0 >> 6;
        // ---- QK^T: S[16q x 64k], fragment-major K loads (coalesced) ----
        f32x4 s[4];
        #pragma unroll
        for (int j4 = 0; j4 < 4; ++j4) s[j4] = (f32x4){0.f,0.f,0.f,0.f};
        #pragma unroll
        for (int j4 = 0; j4 < 4; ++j4)
            #pragma unroll
            for (int ks = 0; ks < 3; ++ks) {
                bf16x8 kf = *(const bf16x8*)&kb[(((kvb16 + j4)*3 + ks)<<9) + lane*8];
                s[j4] = __builtin_amdgcn_mfma_f32_16x16x32_bf16(qf[ks], kf, s[j4], 0, 0, 0);
            }
        // ---- online softmax (exp2 domain), DPP reductions, packed P stores ----
        float alpha[4];
        #pragma unroll
        for (int r = 0; r < 4; ++r) {
            float tm = fmaxf(fmaxf(s[0][r], s[1][r]), fmaxf(s[2][r], s[3][r]));
            tm = rowmax16(tm);
            float mn = fmaxf(mrow[r], tm);
            alpha[r] = exp2f(mrow[r] - mn);
            float p0 = exp2f(s[0][r] - mn);
            float p1 = exp2f(s[1][r] - mn);
            float p2 = exp2f(s[2][r] - mn);
            float p3 = exp2f(s[3][r] - mn);
            float ts = rowsum16((p0+p1)+(p2+p3));
            lrow[r] = lrow[r]*alpha[r] + ts;
            mrow[r] = mn;
            const int prow = quad*4 + r;
            unsigned int lo = (unsigned int)f2bu(p0) | ((unsigned int)f2bu(p1) << 16);
            unsigned int hi = (unsigned int)f2bu(p2) | ((unsigned int)f2bu(p3) << 16);
            unsigned long long pk = (unsigned long long)lo | ((unsigned long long)hi << 32);
            *(unsigned long long*)&pw[prow*PSTR + col*4] = pk;
        }
        if (__any(alpha[0]+alpha[1]+alpha[2]+alpha[3] < 4.f)) {
            #pragma unroll
            for (int i = 0; i < 5; ++i)
                #pragma unroll
                for (int r = 0; r < 4; ++r) oacc[i][r] *= alpha[r];
        }
        bf16x8 pf0 = *(const bf16x8*)&pw[col*PSTR + quad*8];
        bf16x8 pf1 = *(const bf16x8*)&pw[col*PSTR + 32 + quad*8];
        #pragma unroll
        for (int nt = 0; nt < 5; ++nt) {
            bf16x8 vf0 = *(const bf16x8*)&vb[((kvt*10 + nt)<<9) + lane*8];
            bf16x8 vf1 = *(const bf16x8*)&vb[((kvt*10 + 5 + nt)<<9) + lane*8];
            oacc[nt] = __builtin_amdgcn_mfma_f32_16x16x32_bf16(pf0, vf0, oacc[nt], 0, 0, 0);
            oacc[nt] = __builtin_amdgcn_mfma_f32_16x16x32_bf16(pf1, vf1, oacc[nt], 0, 0, 0);
        }
    }

    // ---- merge the two KV halves ----
    __syncthreads();
    if (half) {
        f32x4 mv, lv;
        #pragma unroll
        for (int r = 0; r < 4; ++r) { mv[r] = mrow[r]; lv[r] = lrow[r]; }
        Msm[qg*64 + lane] = mv;
        Lsm[qg*64 + lane] = lv;
        #pragma unroll
        for (int nt = 0; nt < 5; ++nt) Osm[(qg*5 + nt)*64 + lane] = oacc[nt];
    }
    __syncthreads();
    if (!half) {
        f32x4 mB = Msm[qg*64 + lane];
        f32x4 lB = Lsm[qg*64 + lane];
        float aA[4], aB[4], inv[4];
        #pragma unroll
        for (int r = 0; r < 4; ++r) {
            float ms = fmaxf(mrow[r], mB[r]);
            aA[r] = exp2f(mrow[r] - ms);
            aB[r] = exp2f(mB[r] - ms);
            float ls = lrow[r]*aA[r] + lB[r]*aB[r];
            inv[r] = 1.f / ls;
        }
        #pragma unroll
        for (int nt = 0; nt < 5; ++nt) {
            f32x4 oB = Osm[(qg*5 + nt)*64 + lane];
            int d = nt*16 + col;
            if (d < HDIM) {
                #pragma unroll
                for (int r = 0; r < 4; ++r) {
                    int qrow = q0 + quad*4 + r;
                    o[((long)b*NTOK + qrow)*H + h*HDIM + d] = f2b((oacc[nt][r]*aA[r] + oB[r]*aB[r])*inv[r]);
                }
            }
        }
    }
}

extern "C" void kernel_launch(void* const* d_in, const int* in_sizes, int n_in,
                              void* d_out, int out_size, void* d_ws, size_t ws_size,
                              hipStream_t stream) {
    const float* x      = (const float*)d_in[0];
    const float* c      = (const float*)d_in[1];
    const float* w_mod  = (const float*)d_in[2];
    const float* b_mod  = (const float*)d_in[3];
    const float* w_qkv  = (const float*)d_in[4];
    const float* b_qkv  = (const float*)d_in[5];
    const float* g_q    = (const float*)d_in[6];
    const float* g_k    = (const float*)d_in[7];
    const float* w_proj = (const float*)d_in[8];
    const float* b_proj = (const float*)d_in[9];
    const float* w1     = (const float*)d_in[10];
    const float* b1     = (const float*)d_in[11];
    const float* w2     = (const float*)d_in[12];
    const float* b2     = (const float*)d_in[13];
    float* out = (float*)d_out;   // f32; also serves as x1 (residual after attn branch)

    // ---- workspace layout (runtime-sized, chunked row pipeline) ----
    char* ws = (char*)d_ws;
    size_t off = 0;
    auto alloc = [&](size_t bytes) { void* p = ws + off; off += (bytes + 255) & ~(size_t)255; return p; };
    float* modb  = (float*)alloc((size_t)NB*H6*4);
    bf16* wqkvT  = (bf16*)alloc((size_t)H3*H*2);
    bf16* wprojT = (bf16*)alloc((size_t)H*H*2);
    bf16* w1T    = (bf16*)alloc((size_t)MLPD*H*2);
    bf16* w2T    = (bf16*)alloc((size_t)H*MLPD*2);
    const size_t pers = off;

    // per-row chunk bytes: R1 (qkv|o|h overlay) = 9216, R2 (qln+kln+vt | xn overlay) = 8704
    int nchunk = 1;
    while (nchunk < 16 && pers + (size_t)(ROWS/nchunk)*(9216+8704) > ws_size) nchunk <<= 1;
    const int Rc = ROWS / nchunk;       // rows per chunk (multiple of 1024)
    const int Bc = NB / nchunk;         // batches per chunk

    char* R1 = ws + pers;                       // Rc*9216 bytes
    char* R2 = R1 + (size_t)Rc*9216;            // Rc*8704 bytes
    bf16* qkvc = (bf16*)R1;                     // Rc*3456 elems, live: qkv-gemm -> qk_ln/v_t
    bf16* oc   = (bf16*)R1;                     // Rc*1152, live: attn -> proj
    bf16* hc   = (bf16*)R1;                     // Rc*4608, live: mlp1 -> mlp2
    bf16* xnc  = (bf16*)R2;                     // Rc*1152, live: ln -> gemm (twice)
    bf16* qlnc = (bf16*)R2;                     // Bc*16*1024*96  (q row-major)
    bf16* klnc = (bf16*)(R2 + (size_t)Rc*3072); // Bc*16*98304 elems (K fragment-major, 192KB/bh)
    bf16* vtc  = (bf16*)(R2 + (size_t)Rc*6144); // Bc*16*81920 elems (V fragment-major, 160KB/bh)
    float* modp = (float*)R1;                   // mod partials (dead before first chunk kernel writes R1)

    // ---- setup (once) ----
    mod_partial_kernel<<<dim3(H6/256, KSPLIT), 256, 0, stream>>>(c, w_mod, modp);
    mod_reduce_kernel<<<dim3(NB*H6/256), 256, 0, stream>>>(modp, b_mod, modb);
    transpose_kernel<<<dim3(H3/32,  H/32),   256, 0, stream>>>(w_qkv,  wqkvT,  H,    H3);
    transpose_kernel<<<dim3(H/32,   H/32),   256, 0, stream>>>(w_proj, wprojT, H,    H);
    transpose_kernel<<<dim3(MLPD/32,H/32),   256, 0, stream>>>(w1,     w1T,    H,    MLPD);
    transpose_kernel<<<dim3(H/32,   MLPD/32),256, 0, stream>>>(w2,     w2T,    MLPD, H);

    // ---- chunked pipeline ----
    for (int ci = 0; ci < nchunk; ++ci) {
        const int row0 = ci * Rc;
        // xn = LN(x)*(1+sc_msa)+sh_msa
        ln_mod_kernel<<<dim3(Rc), 256, 0, stream>>>(x, modb, 0, H, xnc, row0);
        // qkv = xn @ w_qkv + b_qkv
        gemm_bt<0><<<dim3((H3/128)*(Rc/128)), 256, 0, stream>>>(xnc, wqkvT, b_qkv, nullptr, nullptr, qkvc, nullptr, Rc, H3, H, 0);
        // q/k layernorm (q row-major, k fragment-major), v fragment-major transpose
        qk_ln_kernel<<<dim3(Bc*NHEAD*NTOK/4), 256, 0, stream>>>(qkvc, g_q, g_k, qlnc, klnc);
        v_transpose_kernel<<<dim3(NTOK/64, NHEAD, Bc), 256, 0, stream>>>(qkvc, vtc);
        // attention (1D grid, XCD-aware bh mapping; 8 waves: 4 q-groups x 2 kv halves)
        attn_kernel<<<dim3(256*Bc), 512, 0, stream>>>(qlnc, klnc, vtc, oc, Bc);
        // x1 = x + g_msa*(o@w_proj+b_proj)   -> f32 in d_out
        gemm_bt<2><<<dim3((H/128)*(Rc/128)), 256, 0, stream>>>(oc, wprojT, b_proj, x, modb + 2*H, nullptr, out, Rc, H, H, row0);
        // xn2 = LN(x1)*(1+sc_mlp)+sh_mlp
        ln_mod_kernel<<<dim3(Rc), 256, 0, stream>>>(out, modb, 3*H, 4*H, xnc, row0);
        // h = gelu(xn2@w1+b1)
        gemm_bt<1><<<dim3((MLPD/128)*(Rc/128)), 256, 0, stream>>>(xnc, w1T, b1, nullptr, nullptr, hc, nullptr, Rc, MLPD, H, 0);
        // out = x1 + g_mlp*(h@w2+b2)   (f32, in-place residual)
        gemm_bt<2><<<dim3((H/128)*(Rc/128)), 256, 0, stream>>>(hc, w2T, b2, out, modb + 5*H, nullptr, out, Rc, H, MLPD, row0);
    }
}